// Round 18
// baseline (80.321 us; speedup 1.0000x reference)
//
#include <hip/hip_runtime.h>
#include <hip/hip_bf16.h>

// BarlowTwins loss: logits[b,n,m] = sum_s z1[b,s,n]*z2[b,s,m]  (B=8, S=256, N=M=2048)
// loss = mean_{b,m}( LSE_n(logits[b,:,m]) - logits[b,m,m] )
//
// Round-18 = R15 gemm (29.1us best family: block 512m x 256n, wave owns 64m (2 strips,
// bf 128 regs) x full 256n, grid 256 = 1 block/CU, 132KB LDS panel, exp2-sum) with:
//  (a) SPLIT mega-stage: stage rows 0..127 + B -> barrier -> compute subs 0..3 while
//      staging rows 128..255 (one row-group after each subtile; L2 delivery hides under
//      MFMAs) -> barrier -> compute subs 4..7 barrier-free. Overlaps ~half the formerly
//      exposed ~6us prologue.
//  (b) fused merge+final kernel (32 blocks x 512thr), arrival counter zeroed by the
//      GEMM kernel (block0/thread0 plain store, visible at dispatch boundary) -- R17's
//      64B hipMemsetAsync cost a ~40us dispatch slot in the graph; this is free.

#define NN 2048
#define SK 256
#define LDST 264
#define LOG2E 1.4426950408889634f
#define LN2   0.6931471805599453f
#define COFF  96.0f

typedef __attribute__((ext_vector_type(8))) short short8;
typedef __attribute__((ext_vector_type(16))) float f32x16;

__device__ __forceinline__ unsigned short f2bf(float f) {
    __hip_bfloat16 h = __float2bfloat16(f);
    unsigned short u; __builtin_memcpy(&u, &h, 2); return u;
}

__device__ __forceinline__ float exp2g(float x) {
#if __has_builtin(__builtin_amdgcn_exp2f)
    return __builtin_amdgcn_exp2f(x);
#else
    return exp2f(x);
#endif
}

__device__ __forceinline__ float log2g(float x) {
#if __has_builtin(__builtin_amdgcn_logf)
    return __builtin_amdgcn_logf(x);
#else
    return log2f(x);
#endif
}

__global__ __launch_bounds__(512) void gemm_lse_kernel(
    const float* __restrict__ z1, const float* __restrict__ z2,
    float* __restrict__ ws_sum, float* __restrict__ ws_diag,
    unsigned int* __restrict__ ctr)
{
    __shared__ unsigned short lds[256 * LDST];   // 132 KB: whole 256n x 256k panel

    // zero the epilogue arrival counter (one thread chip-wide; free vs a memset launch)
    if (blockIdx.x == 0 && threadIdx.x == 0) ctr[0] = 0u;

    const int bid  = blockIdx.x;
    const int b    = bid & 7;          // XCD-aligned batch
    const int tile = bid >> 3;
    const int mb   = tile & 3;         // 4 m-blocks of 512
    const int ns   = tile >> 2;        // 8 n-splits of 256
    const int tid  = threadIdx.x;
    const int lane = tid & 63;
    const int w    = tid >> 6;         // wave 0..7 owns 64 m
    const int col  = lane & 31;
    const int kg   = lane >> 5;

    const int m0      = mb * 512 + w * 64;   // strip0; strip1 = +32
    const int mcol0   = m0 + col;
    const int mcol1   = m0 + 32 + col;
    const int n_start = ns * 256;

    const float* z1b = z1 + (size_t)b * SK * NN;
    const float* z2b = z2 + (size_t)b * SK * NN;

    const int kc  = (w << 1) | kg;     // k-chunk 0..15 (16 s each)
    const int row = col;               // base n-row

    // stage one 32-row group of the panel (thread covers 16 s x 1 row)
    auto stage_rg = [&](int rg) {
        const int nrow = rg * 32 + row;
        const float* p = z1b + (size_t)(kc * 16) * NN + (n_start + nrow);
        float t0[8], t1[8];
        #pragma unroll
        for (int j = 0; j < 8; ++j) t0[j] = p[(size_t)j * NN];
        #pragma unroll
        for (int j = 0; j < 8; ++j) t1[j] = p[(size_t)(j + 8) * NN];
        short8 pk0, pk1;
        #pragma unroll
        for (int j = 0; j < 8; ++j) { pk0[j] = (short)f2bf(t0[j]); pk1[j] = (short)f2bf(t1[j]); }
        *(short8*)(lds + nrow * LDST + kc * 16)     = pk0;
        *(short8*)(lds + nrow * LDST + kc * 16 + 8) = pk1;
    };

    // ---- phase 1: stage rows 0..127 ----
    #pragma unroll
    for (int rg = 0; rg < 4; ++rg) stage_rg(rg);

    // ---- B fragments: 2 strips x K=256, coalesced f32 column loads, x log2e ----
    short8 bf0[16], bf1[16];
    #pragma unroll
    for (int ks = 0; ks < 16; ++ks) {
        short8 p0, p1;
        #pragma unroll
        for (int j = 0; j < 8; ++j) {
            const int s = ks * 16 + kg * 8 + j;
            p0[j] = (short)f2bf(z2b[(size_t)s * NN + mcol0] * LOG2E);
            p1[j] = (short)f2bf(z2b[(size_t)s * NN + mcol1] * LOG2E);
        }
        bf0[ks] = p0; bf1[ks] = p1;
    }

    float srun0 = 0.0f, srun1 = 0.0f;

    __syncthreads();   // barrier #1: rows 0..127 + B landed

// compute one 32-n subtile (16 ds_read_b128 + 32 MFMA + diag + 32 exp2)
#define SUBTILE(SUB)                                                                 \
    {                                                                                \
        const unsigned short* abase = lds + (32 * (SUB) + col) * LDST + kg * 8;      \
        f32x16 acc0, acc1;                                                           \
        _Pragma("unroll")                                                            \
        for (int r = 0; r < 16; ++r) { acc0[r] = -COFF; acc1[r] = -COFF; }           \
        _Pragma("unroll")                                                            \
        for (int ks = 0; ks < 16; ++ks) {                                            \
            short8 af = *(const short8*)(abase + ks * 16);                           \
            acc0 = __builtin_amdgcn_mfma_f32_32x32x16_bf16(af, bf0[ks], acc0, 0, 0, 0); \
            acc1 = __builtin_amdgcn_mfma_f32_32x32x16_bf16(af, bf1[ks], acc1, 0, 0, 0); \
        }                                                                            \
        const int nsub = n_start + 32 * (SUB);                                       \
        if (nsub == m0) {                                                            \
            _Pragma("unroll")                                                        \
            for (int r = 0; r < 16; ++r) {                                           \
                const int rw = (r & 3) + 8 * (r >> 2) + 4 * kg;                      \
                if (rw == col) ws_diag[b * NN + mcol0] = acc0[r];                    \
            }                                                                        \
        }                                                                            \
        if (nsub == m0 + 32) {                                                       \
            _Pragma("unroll")                                                        \
            for (int r = 0; r < 16; ++r) {                                           \
                const int rw = (r & 3) + 8 * (r >> 2) + 4 * kg;                      \
                if (rw == col) ws_diag[b * NN + mcol1] = acc1[r];                    \
            }                                                                        \
        }                                                                            \
        {                                                                            \
            float e0 = 0, e1 = 0, e2 = 0, e3 = 0;                                    \
            _Pragma("unroll")                                                        \
            for (int r = 0; r < 16; r += 4) {                                        \
                e0 += exp2g(acc0[r]);     e1 += exp2g(acc0[r + 1]);                  \
                e2 += exp2g(acc0[r + 2]); e3 += exp2g(acc0[r + 3]);                  \
            }                                                                        \
            srun0 += (e0 + e1) + (e2 + e3);                                          \
        }                                                                            \
        {                                                                            \
            float e0 = 0, e1 = 0, e2 = 0, e3 = 0;                                    \
            _Pragma("unroll")                                                        \
            for (int r = 0; r < 16; r += 4) {                                        \
                e0 += exp2g(acc1[r]);     e1 += exp2g(acc1[r + 1]);                  \
                e2 += exp2g(acc1[r + 2]); e3 += exp2g(acc1[r + 3]);                  \
            }                                                                        \
            srun1 += (e0 + e1) + (e2 + e3);                                          \
        }                                                                            \
    }

    // ---- phase 2: compute subs 0..3, staging rows 128..255 in the gaps ----
    SUBTILE(0) stage_rg(4);
    SUBTILE(1) stage_rg(5);
    SUBTILE(2) stage_rg(6);
    SUBTILE(3) stage_rg(7);

    __syncthreads();   // barrier #2: rows 128..255 landed

    // ---- phase 3: compute subs 4..7, barrier-free ----
    SUBTILE(4)
    SUBTILE(5)
    SUBTILE(6)
    SUBTILE(7)
#undef SUBTILE

    // combine kg halves; one writer per m-col (wave owns its cols exclusively)
    srun0 += __shfl_xor(srun0, 32);
    srun1 += __shfl_xor(srun1, 32);
    if (kg == 0) {
        ws_sum[(b * 8 + ns) * NN + mcol0] = srun0;
        ws_sum[(b * 8 + ns) * NN + mcol1] = srun1;
    }
}

// ---------------- fused merge + final (one small kernel, no memset needed) ----------------
__global__ __launch_bounds__(512) void merge_final_kernel(
    const float* __restrict__ ws_sum, const float* __restrict__ ws_diag,
    float* __restrict__ partial, unsigned int* __restrict__ ctr,
    float* __restrict__ out)
{
    __shared__ float red[8];

    const int gid = blockIdx.x * 512 + threadIdx.x;   // 0..16383
    const int b = gid >> 11, m = gid & (NN - 1);

    float S = 0.0f;
    #pragma unroll
    for (int slot = 0; slot < 8; ++slot)
        S += ws_sum[(b * 8 + slot) * NN + m];
    float c = log2g(S) - ws_diag[gid];   // (LSE' - diag') in log2 units

    #pragma unroll
    for (int d = 1; d < 64; d <<= 1) c += __shfl_xor(c, d);
    if ((threadIdx.x & 63) == 0) red[threadIdx.x >> 6] = c;
    __syncthreads();

    if (threadIdx.x == 0) {
        float s = 0.0f;
        #pragma unroll
        for (int i = 0; i < 8; ++i) s += red[i];
        partial[blockIdx.x] = s;
        __threadfence();                          // release partial (1 thread/block)
        unsigned int old = atomicAdd(ctr, 1u);
        if (old == 31u) {                         // last of 32 blocks finalizes
            __threadfence();                      // acquire
            volatile const float* vp = partial;
            float tot = 0.0f;
            for (int i = 0; i < 32; ++i) tot += vp[i];   // fixed order
            out[0] = tot * (LN2 / 16384.0f);
        }
    }
}

extern "C" void kernel_launch(void* const* d_in, const int* in_sizes, int n_in,
                              void* d_out, int out_size, void* d_ws, size_t ws_size,
                              hipStream_t stream)
{
    const float* z1 = (const float*)d_in[0];
    const float* z2 = (const float*)d_in[1];
    float* ws  = (float*)d_ws;
    float* out = (float*)d_out;

    // ws layout (floats): sum[8][8][2048] | diag[8][2048] | partial[32] | ctr int[1]
    float* ws_sum  = ws;
    float* ws_diag = ws + 131072;
    float* ws_part = ws + 147456;
    unsigned int* ws_ctr = (unsigned int*)(ws + 147488);

    gemm_lse_kernel<<<dim3(256), dim3(512), 0, stream>>>(z1, z2, ws_sum, ws_diag, ws_ctr);
    merge_final_kernel<<<dim3(32), dim3(512), 0, stream>>>(ws_sum, ws_diag, ws_part, ws_ctr, out);
}

// Round 19
// 32.032 us; speedup vs baseline: 2.5076x; 2.5076x over previous
//
#include <hip/hip_runtime.h>
#include <hip/hip_bf16.h>

// BarlowTwins loss: logits[b,n,m] = sum_s z1[b,s,n]*z2[b,s,m]  (B=8, S=256, N=M=2048)
// loss = mean_{b,m}( LSE_n(logits[b,:,m]) - logits[b,m,m] )
//
// Round-19 = three PROVEN pieces, nothing new:
//  - gemm: byte-exact R15 (29.1us best: block 512m x 256n, wave owns 64m (2 strips,
//    bf 128 regs) x full 256n, grid 256 = 1/CU, 132KB LDS mega-stage, ONE barrier,
//    barrier-free compute, exp2-sum no max tracking) + one-line ctr zero at entry
//    (R18-validated register-neutral; saves the memset dispatch).
//  - merge+final fused in one 32-block kernel (R17-validated): per-block fixed-order
//    reduce -> partial; last arrival (device atomic + threadfence, 1 thread/block only)
//    sums 32 partials in fixed order -> out. Deterministic.
//  Lessons baked in: no fences in the big kernel (R16 +45us), no tiny memset dispatch
//  (R17 +40us), no extra live state in compute (R12/R14/R18 spills at the 128-reg wall).

#define NN 2048
#define SK 256
#define LDST 264
#define LOG2E 1.4426950408889634f
#define LN2   0.6931471805599453f
#define COFF  96.0f

typedef __attribute__((ext_vector_type(8))) short short8;
typedef __attribute__((ext_vector_type(16))) float f32x16;

__device__ __forceinline__ unsigned short f2bf(float f) {
    __hip_bfloat16 h = __float2bfloat16(f);
    unsigned short u; __builtin_memcpy(&u, &h, 2); return u;
}

__device__ __forceinline__ float exp2g(float x) {
#if __has_builtin(__builtin_amdgcn_exp2f)
    return __builtin_amdgcn_exp2f(x);
#else
    return exp2f(x);
#endif
}

__device__ __forceinline__ float log2g(float x) {
#if __has_builtin(__builtin_amdgcn_logf)
    return __builtin_amdgcn_logf(x);
#else
    return log2f(x);
#endif
}

__global__ __launch_bounds__(512) void gemm_lse_kernel(
    const float* __restrict__ z1, const float* __restrict__ z2,
    float* __restrict__ ws_sum, float* __restrict__ ws_diag,
    unsigned int* __restrict__ ctr)
{
    __shared__ unsigned short lds[256 * LDST];   // 132 KB: whole 256n x 256k panel

    // zero the epilogue arrival counter (register-neutral; saves a memset dispatch)
    if (blockIdx.x == 0 && threadIdx.x == 0) ctr[0] = 0u;

    const int bid  = blockIdx.x;
    const int b    = bid & 7;          // XCD-aligned batch
    const int tile = bid >> 3;
    const int mb   = tile & 3;         // 4 m-blocks of 512
    const int ns   = tile >> 2;        // 8 n-splits of 256
    const int tid  = threadIdx.x;
    const int lane = tid & 63;
    const int w    = tid >> 6;         // wave 0..7 owns 64 m
    const int col  = lane & 31;
    const int kg   = lane >> 5;

    const int m0      = mb * 512 + w * 64;   // strip0; strip1 = +32
    const int mcol0   = m0 + col;
    const int mcol1   = m0 + 32 + col;
    const int n_start = ns * 256;

    const float* z1b = z1 + (size_t)b * SK * NN;
    const float* z2b = z2 + (size_t)b * SK * NN;

    // ---- mega-stage: thread (kc,row) stages 8 rows x 16 s of the 256x256 panel ----
    const int kc  = (w << 1) | kg;     // k-chunk 0..15 (16 s each)
    const int row = col;               // base n-row
    #pragma unroll
    for (int rg = 0; rg < 8; ++rg) {
        const int nrow = rg * 32 + row;
        const float* p = z1b + (size_t)(kc * 16) * NN + (n_start + nrow);
        float t0[8], t1[8];
        #pragma unroll
        for (int j = 0; j < 8; ++j) t0[j] = p[(size_t)j * NN];
        #pragma unroll
        for (int j = 0; j < 8; ++j) t1[j] = p[(size_t)(j + 8) * NN];
        short8 pk0, pk1;
        #pragma unroll
        for (int j = 0; j < 8; ++j) { pk0[j] = (short)f2bf(t0[j]); pk1[j] = (short)f2bf(t1[j]); }
        *(short8*)(lds + nrow * LDST + kc * 16)     = pk0;
        *(short8*)(lds + nrow * LDST + kc * 16 + 8) = pk1;
    }

    // ---- B fragments: 2 strips x K=256, coalesced f32 column loads, x log2e ----
    short8 bf0[16], bf1[16];
    #pragma unroll
    for (int ks = 0; ks < 16; ++ks) {
        short8 p0, p1;
        #pragma unroll
        for (int j = 0; j < 8; ++j) {
            const int s = ks * 16 + kg * 8 + j;
            p0[j] = (short)f2bf(z2b[(size_t)s * NN + mcol0] * LOG2E);
            p1[j] = (short)f2bf(z2b[(size_t)s * NN + mcol1] * LOG2E);
        }
        bf0[ks] = p0; bf1[ks] = p1;
    }

    float srun0 = 0.0f, srun1 = 0.0f;

    __syncthreads();   // the ONLY barrier: panel + B landed

    #pragma unroll 2
    for (int sub = 0; sub < 8; ++sub) {
        const unsigned short* abase = lds + (32 * sub + col) * LDST + kg * 8;

        f32x16 acc0, acc1;
        #pragma unroll
        for (int r = 0; r < 16; ++r) { acc0[r] = -COFF; acc1[r] = -COFF; }

        #pragma unroll
        for (int ks = 0; ks < 16; ++ks) {
            short8 af = *(const short8*)(abase + ks * 16);
            acc0 = __builtin_amdgcn_mfma_f32_32x32x16_bf16(af, bf0[ks], acc0, 0, 0, 0);
            acc1 = __builtin_amdgcn_mfma_f32_32x32x16_bf16(af, bf1[ks], acc1, 0, 0, 0);
        }

        // diagonal capture (acc = logit' - 96; offset cancels in merge)
        const int nsub = n_start + 32 * sub;
        if (nsub == m0) {
            #pragma unroll
            for (int r = 0; r < 16; ++r) {
                const int rw = (r & 3) + 8 * (r >> 2) + 4 * kg;
                if (rw == col) ws_diag[b * NN + mcol0] = acc0[r];
            }
        }
        if (nsub == m0 + 32) {
            #pragma unroll
            for (int r = 0; r < 16; ++r) {
                const int rw = (r & 3) + 8 * (r >> 2) + 4 * kg;
                if (rw == col) ws_diag[b * NN + mcol1] = acc1[r];
            }
        }

        // exp2-sum, 4 independent chains per strip
        {
            float e0 = 0, e1 = 0, e2 = 0, e3 = 0;
            #pragma unroll
            for (int r = 0; r < 16; r += 4) {
                e0 += exp2g(acc0[r]);     e1 += exp2g(acc0[r + 1]);
                e2 += exp2g(acc0[r + 2]); e3 += exp2g(acc0[r + 3]);
            }
            srun0 += (e0 + e1) + (e2 + e3);
        }
        {
            float e0 = 0, e1 = 0, e2 = 0, e3 = 0;
            #pragma unroll
            for (int r = 0; r < 16; r += 4) {
                e0 += exp2g(acc1[r]);     e1 += exp2g(acc1[r + 1]);
                e2 += exp2g(acc1[r + 2]); e3 += exp2g(acc1[r + 3]);
            }
            srun1 += (e0 + e1) + (e2 + e3);
        }
    }

    // combine kg halves; one writer per m-col (wave owns its cols exclusively)
    srun0 += __shfl_xor(srun0, 32);
    srun1 += __shfl_xor(srun1, 32);
    if (kg == 0) {
        ws_sum[(b * 8 + ns) * NN + mcol0] = srun0;
        ws_sum[(b * 8 + ns) * NN + mcol1] = srun1;
    }
}

// ---------------- fused merge + final (one small kernel) ----------------
__global__ __launch_bounds__(512) void merge_final_kernel(
    const float* __restrict__ ws_sum, const float* __restrict__ ws_diag,
    float* __restrict__ partial, unsigned int* __restrict__ ctr,
    float* __restrict__ out)
{
    __shared__ float red[8];

    const int gid = blockIdx.x * 512 + threadIdx.x;   // 0..16383
    const int b = gid >> 11, m = gid & (NN - 1);

    float S = 0.0f;
    #pragma unroll
    for (int slot = 0; slot < 8; ++slot)
        S += ws_sum[(b * 8 + slot) * NN + m];
    float c = log2g(S) - ws_diag[gid];   // (LSE' - diag') in log2 units

    #pragma unroll
    for (int d = 1; d < 64; d <<= 1) c += __shfl_xor(c, d);
    if ((threadIdx.x & 63) == 0) red[threadIdx.x >> 6] = c;
    __syncthreads();

    if (threadIdx.x == 0) {
        float s = 0.0f;
        #pragma unroll
        for (int i = 0; i < 8; ++i) s += red[i];
        partial[blockIdx.x] = s;
        __threadfence();                          // release partial (1 thread/block)
        unsigned int old = atomicAdd(ctr, 1u);
        if (old == 31u) {                         // last of 32 blocks finalizes
            __threadfence();                      // acquire
            volatile const float* vp = partial;
            float tot = 0.0f;
            for (int i = 0; i < 32; ++i) tot += vp[i];   // fixed order
            out[0] = tot * (LN2 / 16384.0f);
        }
    }
}

extern "C" void kernel_launch(void* const* d_in, const int* in_sizes, int n_in,
                              void* d_out, int out_size, void* d_ws, size_t ws_size,
                              hipStream_t stream)
{
    const float* z1 = (const float*)d_in[0];
    const float* z2 = (const float*)d_in[1];
    float* ws  = (float*)d_ws;
    float* out = (float*)d_out;

    // ws layout (floats): sum[8][8][2048] | diag[8][2048] | partial[32] | ctr int[1]
    float* ws_sum  = ws;
    float* ws_diag = ws + 131072;
    float* ws_part = ws + 147456;
    unsigned int* ws_ctr = (unsigned int*)(ws + 147488);

    gemm_lse_kernel<<<dim3(256), dim3(512), 0, stream>>>(z1, z2, ws_sum, ws_diag, ws_ctr);
    merge_final_kernel<<<dim3(32), dim3(512), 0, stream>>>(ws_sum, ws_diag, ws_part, ws_ctr, out);
}

// Round 20
// 29.196 us; speedup vs baseline: 2.7511x; 1.0971x over previous
//
#include <hip/hip_runtime.h>
#include <hip/hip_bf16.h>

// BarlowTwins loss: logits[b,n,m] = sum_s z1[b,s,n]*z2[b,s,m]  (B=8, S=256, N=M=2048)
// loss = mean_{b,m}( LSE_n(logits[b,:,m]) - logits[b,m,m] )
//
// FINAL (round-20) = byte-exact round-15, the measured optimum (29.1us) of the search:
//  - gemm: 256 blocks (1/CU, b=bid&7 XCD-aligned) x 512 thr. Block = 512m x 256n.
//    Wave owns 64m (2 strips; B-frags = 128 VGPR = the full arch file the compiler
//    allocates) x full 256n. Whole 256n x 256k A panel staged once into 132KB LDS
//    (stride 264: write & read both <=2-way bank aliasing = free). ONE barrier, then
//    8 subtiles of pure {16 ds_read_b128 + 32 MFMA + diag + 32 exp2} with no barriers.
//    No max tracking: z2 pre-scaled by log2e, acc init -96 (headroom ~2^33);
//    LSE - diag = ln2*(log2(S) - diag_acc), offset cancels.
//  - merge (64 blk): sum 8 n-partials, log2, subtract diag, block-reduce.
//  - final (1 blk): 64-partial fixed-order reduce, * ln2/16384.
// Cost structure (measured): ~6us exposed L2 panel delivery (near I/O lower bound for
// 160KB-LDS tilings), ~16us compute at the 128-VGPR wall, ~3us epilogue. Fusions,
// occupancy, vmcnt pipelines, gload_lds, and decomposition swaps all measured worse
// (rounds 3,5-14,16-19).

#define NN 2048
#define SK 256
#define LDST 264
#define LOG2E 1.4426950408889634f
#define LN2   0.6931471805599453f
#define COFF  96.0f

typedef __attribute__((ext_vector_type(8))) short short8;
typedef __attribute__((ext_vector_type(16))) float f32x16;

__device__ __forceinline__ unsigned short f2bf(float f) {
    __hip_bfloat16 h = __float2bfloat16(f);
    unsigned short u; __builtin_memcpy(&u, &h, 2); return u;
}

__device__ __forceinline__ float exp2g(float x) {
#if __has_builtin(__builtin_amdgcn_exp2f)
    return __builtin_amdgcn_exp2f(x);
#else
    return exp2f(x);
#endif
}

__device__ __forceinline__ float log2g(float x) {
#if __has_builtin(__builtin_amdgcn_logf)
    return __builtin_amdgcn_logf(x);
#else
    return log2f(x);
#endif
}

__global__ __launch_bounds__(512) void gemm_lse_kernel(
    const float* __restrict__ z1, const float* __restrict__ z2,
    float* __restrict__ ws_sum, float* __restrict__ ws_diag)
{
    __shared__ unsigned short lds[256 * LDST];   // 132 KB: whole 256n x 256k panel

    const int bid  = blockIdx.x;
    const int b    = bid & 7;          // XCD-aligned batch
    const int tile = bid >> 3;
    const int mb   = tile & 3;         // 4 m-blocks of 512
    const int ns   = tile >> 2;        // 8 n-splits of 256
    const int tid  = threadIdx.x;
    const int lane = tid & 63;
    const int w    = tid >> 6;         // wave 0..7 owns 64 m
    const int col  = lane & 31;
    const int kg   = lane >> 5;

    const int m0      = mb * 512 + w * 64;   // strip0; strip1 = +32
    const int mcol0   = m0 + col;
    const int mcol1   = m0 + 32 + col;
    const int n_start = ns * 256;

    const float* z1b = z1 + (size_t)b * SK * NN;
    const float* z2b = z2 + (size_t)b * SK * NN;

    // ---- mega-stage: thread (kc,row) stages 8 rows x 16 s of the 256x256 panel ----
    const int kc  = (w << 1) | kg;     // k-chunk 0..15 (16 s each)
    const int row = col;               // base n-row
    #pragma unroll
    for (int rg = 0; rg < 8; ++rg) {
        const int nrow = rg * 32 + row;
        const float* p = z1b + (size_t)(kc * 16) * NN + (n_start + nrow);
        float t0[8], t1[8];
        #pragma unroll
        for (int j = 0; j < 8; ++j) t0[j] = p[(size_t)j * NN];
        #pragma unroll
        for (int j = 0; j < 8; ++j) t1[j] = p[(size_t)(j + 8) * NN];
        short8 pk0, pk1;
        #pragma unroll
        for (int j = 0; j < 8; ++j) { pk0[j] = (short)f2bf(t0[j]); pk1[j] = (short)f2bf(t1[j]); }
        *(short8*)(lds + nrow * LDST + kc * 16)     = pk0;
        *(short8*)(lds + nrow * LDST + kc * 16 + 8) = pk1;
    }

    // ---- B fragments: 2 strips x K=256, coalesced f32 column loads, x log2e ----
    short8 bf0[16], bf1[16];
    #pragma unroll
    for (int ks = 0; ks < 16; ++ks) {
        short8 p0, p1;
        #pragma unroll
        for (int j = 0; j < 8; ++j) {
            const int s = ks * 16 + kg * 8 + j;
            p0[j] = (short)f2bf(z2b[(size_t)s * NN + mcol0] * LOG2E);
            p1[j] = (short)f2bf(z2b[(size_t)s * NN + mcol1] * LOG2E);
        }
        bf0[ks] = p0; bf1[ks] = p1;
    }

    float srun0 = 0.0f, srun1 = 0.0f;

    __syncthreads();   // the ONLY barrier: panel + B landed

    #pragma unroll 2
    for (int sub = 0; sub < 8; ++sub) {
        const unsigned short* abase = lds + (32 * sub + col) * LDST + kg * 8;

        f32x16 acc0, acc1;
        #pragma unroll
        for (int r = 0; r < 16; ++r) { acc0[r] = -COFF; acc1[r] = -COFF; }

        #pragma unroll
        for (int ks = 0; ks < 16; ++ks) {
            short8 af = *(const short8*)(abase + ks * 16);
            acc0 = __builtin_amdgcn_mfma_f32_32x32x16_bf16(af, bf0[ks], acc0, 0, 0, 0);
            acc1 = __builtin_amdgcn_mfma_f32_32x32x16_bf16(af, bf1[ks], acc1, 0, 0, 0);
        }

        // diagonal capture (acc = logit' - 96; offset cancels in merge)
        const int nsub = n_start + 32 * sub;
        if (nsub == m0) {
            #pragma unroll
            for (int r = 0; r < 16; ++r) {
                const int rw = (r & 3) + 8 * (r >> 2) + 4 * kg;
                if (rw == col) ws_diag[b * NN + mcol0] = acc0[r];
            }
        }
        if (nsub == m0 + 32) {
            #pragma unroll
            for (int r = 0; r < 16; ++r) {
                const int rw = (r & 3) + 8 * (r >> 2) + 4 * kg;
                if (rw == col) ws_diag[b * NN + mcol1] = acc1[r];
            }
        }

        // exp2-sum, 4 independent chains per strip
        {
            float e0 = 0, e1 = 0, e2 = 0, e3 = 0;
            #pragma unroll
            for (int r = 0; r < 16; r += 4) {
                e0 += exp2g(acc0[r]);     e1 += exp2g(acc0[r + 1]);
                e2 += exp2g(acc0[r + 2]); e3 += exp2g(acc0[r + 3]);
            }
            srun0 += (e0 + e1) + (e2 + e3);
        }
        {
            float e0 = 0, e1 = 0, e2 = 0, e3 = 0;
            #pragma unroll
            for (int r = 0; r < 16; r += 4) {
                e0 += exp2g(acc1[r]);     e1 += exp2g(acc1[r + 1]);
                e2 += exp2g(acc1[r + 2]); e3 += exp2g(acc1[r + 3]);
            }
            srun1 += (e0 + e1) + (e2 + e3);
        }
    }

    // combine kg halves; one writer per m-col (wave owns its cols exclusively)
    srun0 += __shfl_xor(srun0, 32);
    srun1 += __shfl_xor(srun1, 32);
    if (kg == 0) {
        ws_sum[(b * 8 + ns) * NN + mcol0] = srun0;
        ws_sum[(b * 8 + ns) * NN + mcol1] = srun1;
    }
}

__global__ __launch_bounds__(256) void merge_kernel(
    const float* __restrict__ ws_sum, const float* __restrict__ ws_diag,
    float* __restrict__ partial)
{
    const int gid = blockIdx.x * 256 + threadIdx.x;   // 0..16383
    const int b = gid >> 11, m = gid & (NN - 1);

    float S = 0.0f;
    #pragma unroll
    for (int slot = 0; slot < 8; ++slot)
        S += ws_sum[(b * 8 + slot) * NN + m];
    float c = log2g(S) - ws_diag[gid];   // (LSE' - diag') in log2 units

    #pragma unroll
    for (int d = 1; d < 64; d <<= 1) c += __shfl_xor(c, d);
    __shared__ float red[4];
    if ((threadIdx.x & 63) == 0) red[threadIdx.x >> 6] = c;
    __syncthreads();
    if (threadIdx.x == 0)
        partial[blockIdx.x] = red[0] + red[1] + red[2] + red[3];
}

__global__ void final_kernel(const float* __restrict__ partial, float* __restrict__ out)
{
    float v = partial[threadIdx.x];   // 64 threads
    #pragma unroll
    for (int d = 1; d < 64; d <<= 1) v += __shfl_xor(v, d);
    if (threadIdx.x == 0) out[0] = v * (LN2 / 16384.0f);
}

extern "C" void kernel_launch(void* const* d_in, const int* in_sizes, int n_in,
                              void* d_out, int out_size, void* d_ws, size_t ws_size,
                              hipStream_t stream)
{
    const float* z1 = (const float*)d_in[0];
    const float* z2 = (const float*)d_in[1];
    float* ws  = (float*)d_ws;
    float* out = (float*)d_out;

    // ws layout (floats): sum[8][8][2048] | diag[8][2048] | partial[64]
    float* ws_sum  = ws;
    float* ws_diag = ws + 131072;
    float* ws_part = ws + 147456;

    gemm_lse_kernel<<<dim3(256), dim3(512), 0, stream>>>(z1, z2, ws_sum, ws_diag);
    merge_kernel<<<dim3(64), dim3(256), 0, stream>>>(ws_sum, ws_diag, ws_part);
    final_kernel<<<dim3(1), dim3(64), 0, stream>>>(ws_part, out);
}